// Round 6
// baseline (175.411 us; speedup 1.0000x reference)
//
#include <hip/hip_runtime.h>
#include <hip/hip_bf16.h>
#include <hip/hip_fp16.h>

#define D_MODEL 768
#define NHEADS  12
#define HD      64
#define BATCH   2
#define SEQ     2048
#define NTOK    (BATCH*SEQ)   // 4096
#define NX      ((size_t)NTOK * D_MODEL)     // 3,145,728
#define NW      ((size_t)D_MODEL * D_MODEL)  // 589,824
#define NBH     (BATCH*NHEADS)               // 24
#define SC_LOG2 0.18033688f   // (1/8) * log2(e), folded into Wq/bq

typedef __attribute__((ext_vector_type(8))) short    short8;
typedef __attribute__((ext_vector_type(8))) _Float16 half8;
typedef __attribute__((ext_vector_type(2))) __fp16   fp16x2;
typedef __attribute__((ext_vector_type(4))) float    f32x4;

__device__ __forceinline__ float bf2f(short s) {
    union { unsigned u; float f; } c;
    c.u = ((unsigned)(unsigned short)s) << 16;
    return c.f;
}
__device__ __forceinline__ short f2bf(float f) {
    __hip_bfloat16 h = __float2bfloat16(f);
    return *(short*)&h;
}

#ifdef __has_builtin
#if __has_builtin(__builtin_amdgcn_global_load_lds)
#define HAS_GLD 1
#endif
#if __has_builtin(__builtin_amdgcn_exp2f)
#define EXP2(x) __builtin_amdgcn_exp2f(x)
#else
#define EXP2(x) exp2f(x)
#endif
#if __has_builtin(__builtin_amdgcn_cvt_pkrtz)
#define HAS_PKRTZ 1
#endif
#else
#define EXP2(x) exp2f(x)
#endif
#ifdef HAS_GLD
#define GLD16(gp, lp) __builtin_amdgcn_global_load_lds( \
    (const __attribute__((address_space(1))) void*)(gp), \
    (__attribute__((address_space(3))) void*)(lp), 16, 0, 0)
#endif

#ifdef HAS_PKRTZ
#define PKF16(a, b) __builtin_amdgcn_cvt_pkrtz((a), (b))
#else
#define PKF16(a, b) ((fp16x2){ (__fp16)(a), (__fp16)(b) })
#endif

// ---------------------------------------------------------------------------
// Fused conversion kernel (one launch): every block locally detects the input
// dtype from x's first 4096 halfwords, then converts its assigned slice.
// ---------------------------------------------------------------------------
__global__ __launch_bounds__(256) void fused_conv(
        const void* __restrict__ xin,
        const void* __restrict__ w0, const void* __restrict__ w1,
        const void* __restrict__ w2, const void* __restrict__ w3,
        const void* __restrict__ b0, const void* __restrict__ b1,
        const void* __restrict__ b2, const void* __restrict__ b3,
        short* __restrict__ xc, short* __restrict__ wt,
        short* __restrict__ bc, int* __restrict__ flag)
{
    __shared__ int red[256];
    __shared__ float T[64][65];
    const int tid = threadIdx.x;
    const int F = blockIdx.x;

    {
        const short* xs = (const short*)xin;
        int maxe = 0;
#pragma unroll
        for (int u = 0; u < 16; ++u) {
            int e = ((unsigned short)xs[tid * 16 + u] >> 7) & 0xFF;
            maxe = max(maxe, e);
        }
        red[tid] = maxe;
        __syncthreads();
        for (int s = 128; s > 0; s >>= 1) {
            if (tid < s) red[tid] = max(red[tid], red[tid + s]);
            __syncthreads();
        }
    }
    const bool isf = (red[0] > 140);

    if (F < 3072) {
        const int i = F * 256 + tid;
        if (isf) {
            float4 f = ((const float4*)xin)[i];
            short4 o = { f2bf(f.x), f2bf(f.y), f2bf(f.z), f2bf(f.w) };
            ((short4*)xc)[i] = o;
        } else {
            ((short4*)xc)[i] = ((const short4*)xin)[i];
        }
    } else if (F < 3648) {
        const int G = F - 3072;
        const int z = G / 144, rr = G % 144;
        const int k0 = (rr % 12) * 64, n0 = (rr / 12) * 64;
        const void* src = (z == 0) ? w0 : (z == 1) ? w1 : (z == 2) ? w2 : w3;
        const float sc = (z == 0) ? SC_LOG2 : 1.0f;
        const int la = tid & 15, lb = tid >> 4;
#pragma unroll
        for (int u = 0; u < 4; ++u) {
            const int kr = (lb & 3) + 4 * u + 16 * (lb >> 2);
            if (isf) {
                float4 f = *(const float4*)((const float*)src + (size_t)(k0 + kr) * D_MODEL + n0 + la * 4);
                T[kr][la*4+0] = f.x; T[kr][la*4+1] = f.y; T[kr][la*4+2] = f.z; T[kr][la*4+3] = f.w;
            } else {
                short4 s = *(const short4*)((const short*)src + (size_t)(k0 + kr) * D_MODEL + n0 + la * 4);
                T[kr][la*4+0] = bf2f(s.x); T[kr][la*4+1] = bf2f(s.y);
                T[kr][la*4+2] = bf2f(s.z); T[kr][la*4+3] = bf2f(s.w);
            }
        }
        __syncthreads();
#pragma unroll
        for (int u = 0; u < 4; ++u) {
            const int nr = (lb & 3) + 4 * u + 16 * (lb >> 2);
            short4 o = { f2bf(T[la*4+0][nr] * sc), f2bf(T[la*4+1][nr] * sc),
                         f2bf(T[la*4+2][nr] * sc), f2bf(T[la*4+3][nr] * sc) };
            *(short4*)(wt + (size_t)z * NW + (size_t)(n0 + nr) * D_MODEL + k0 + la * 4) = o;
        }
    } else {
        if (tid == 0) *flag = isf ? 1 : 0;
        const void* srcs[4] = { b0, b1, b2, b3 };
        for (int z = 0; z < 4; ++z) {
            const float sc = (z == 0) ? SC_LOG2 : 1.0f;
            for (int i = tid; i < D_MODEL; i += 256) {
                float v = isf ? ((const float*)srcs[z])[i] : bf2f(((const short*)srcs[z])[i]);
                bc[z * D_MODEL + i] = f2bf(v * sc);
            }
        }
    }
}

// ---------------------------------------------------------------------------
// Fused QKV GEMM v14: 64M x 128N tiles -> grid 64x18 = 1152 blocks (4.5/CU).
// Wave = 32M x 64N (2 mt x 4 nt). Double-buffered GLD16. V segment -> Vt f16
// [bh][dim][SEQ] via single-pass LDS transpose.
// ---------------------------------------------------------------------------
__global__ __launch_bounds__(256) void qkv_gemm(const short* __restrict__ X,
                                                const short* __restrict__ Wt,
                                                const short* __restrict__ bias,
                                                short* __restrict__ qb,
                                                short* __restrict__ kb,
                                                _Float16* __restrict__ Vt)
{
    __shared__ __align__(16) char shbuf[24576];
    short* Als = (short*)shbuf;              // [2][2048]
    short* Bls = (short*)(shbuf + 8192);     // [2][4096]
    _Float16* T = (_Float16*)shbuf;          // epilogue: 128*72 f16 = 18432 B

    const int tid = threadIdx.x;
    const int wave = tid >> 6, lane = tid & 63;
    const int quad = lane >> 4, l16 = lane & 15;
    const int wm = wave & 1, wn = wave >> 1;
    const int m0 = blockIdx.x * 64;
    const int ng = blockIdx.y * 128;

    f32x4 acc[2][4];
#pragma unroll
    for (int nt = 0; nt < 4; ++nt) {
        const float bv = bf2f(bias[ng + wn*64 + nt*16 + l16]);
#pragma unroll
        for (int mt = 0; mt < 2; ++mt) acc[mt][nt] = (f32x4){bv, bv, bv, bv};
    }

    const int row = tid >> 2, ch = (tid & 3) * 8;
#ifdef HAS_GLD
#define QSTAGE(buf, k0) do { \
        GLD16(X  + (size_t)(m0 + row)      * D_MODEL + (k0) + ch, &Als[(buf)*2048 + tid*8]); \
        GLD16(Wt + (size_t)(ng + row)      * D_MODEL + (k0) + ch, &Bls[(buf)*4096 + tid*8]); \
        GLD16(Wt + (size_t)(ng + 64 + row) * D_MODEL + (k0) + ch, &Bls[(buf)*4096 + 2048 + tid*8]); \
    } while (0)
#else
#define QSTAGE(buf, k0) do { \
        short8 r0 = *(const short8*)(X  + (size_t)(m0 + row)      * D_MODEL + (k0) + ch); \
        short8 r2 = *(const short8*)(Wt + (size_t)(ng + row)      * D_MODEL + (k0) + ch); \
        short8 r3 = *(const short8*)(Wt + (size_t)(ng + 64 + row) * D_MODEL + (k0) + ch); \
        *(short8*)&Als[(buf)*2048 + tid*8] = r0; \
        *(short8*)&Bls[(buf)*4096 + tid*8] = r2; \
        *(short8*)&Bls[(buf)*4096 + 2048 + tid*8] = r3; \
    } while (0)
#endif

    QSTAGE(0, 0);
    __syncthreads();

    for (int ks = 0; ks < 24; ++ks) {
        const int cur = ks & 1;
        if (ks + 1 < 24) QSTAGE(cur ^ 1, (ks + 1) * 32);

        short8 a[2], b[4];
#pragma unroll
        for (int mt = 0; mt < 2; ++mt)
            a[mt] = *(const short8*)&Als[cur*2048 + (wm*32 + mt*16 + l16) * 32 + quad*8];
#pragma unroll
        for (int nt = 0; nt < 4; ++nt)
            b[nt] = *(const short8*)&Bls[cur*4096 + (wn*64 + nt*16 + l16) * 32 + quad*8];
#pragma unroll
        for (int mt = 0; mt < 2; ++mt)
#pragma unroll
        for (int nt = 0; nt < 4; ++nt)
            acc[mt][nt] = __builtin_amdgcn_mfma_f32_16x16x32_bf16(a[mt], b[nt], acc[mt][nt], 0, 0, 0);

        __syncthreads();
    }
#undef QSTAGE

    const int seg = blockIdx.y / 6;   // 0=q, 1=k, 2=v
    if (seg < 2) {
        short* out = seg ? kb : qb;
        const int nl = ng - seg * 768;
#pragma unroll
        for (int mt = 0; mt < 2; ++mt)
#pragma unroll
        for (int nt = 0; nt < 4; ++nt) {
            const int n = nl + wn*64 + nt*16 + l16;
#pragma unroll
            for (int r = 0; r < 4; ++r) {
                const int m = m0 + wm*32 + mt*16 + quad*4 + r;
                out[(size_t)m * D_MODEL + n] = f2bf(acc[mt][nt][r]);
            }
        }
    } else {
        // single-pass LDS transpose: T[dim128][tok64+pad8]
        const int batch = m0 >> 11, tokb = m0 & (SEQ - 1);
#pragma unroll
        for (int nt = 0; nt < 4; ++nt) {
            const int dim_l = wn*64 + nt*16 + l16;
#pragma unroll
            for (int mt = 0; mt < 2; ++mt) {
                const int tok_l = wm*32 + mt*16 + quad*4;
                union { _Float16 h4[4]; int2 v; } u;
#pragma unroll
                for (int r = 0; r < 4; ++r) u.h4[r] = (_Float16)acc[mt][nt][r];
                *(int2*)&T[dim_l * 72 + tok_l] = u.v;
            }
        }
        __syncthreads();
#pragma unroll
        for (int u = 0; u < 4; ++u) {
            const int slot = tid + u * 256;           // 0..1023
            const int drow = slot >> 3, chk = slot & 7;
            int4 val = *(const int4*)&T[drow * 72 + chk * 8];
            const int dim_g = ng - 1536 + drow;
            const int h = dim_g >> 6, d = dim_g & 63;
            *(int4*)(Vt + ((size_t)(batch * NHEADS + h) * HD + d) * SEQ + tokb + chk*8) = val;
        }
    }
}

// ---------------------------------------------------------------------------
// Output projection R17: combine FUSED into X-staging. Instead of a separate
// attn_combine kernel + cb round-trip (~5us kernel + gap + 19MB HBM), the X
// tile is built in registers from the two normalized f16 KV-split partials:
//   w_i = exp2(m_i - M) * l_i ;  x = (w1*o1 + w2*o2) / (w1+w2)  -> bf16 -> LDS
// Wt staging keeps GLD16. #pragma unroll 2 lets (m,l) loads CSE across the
// two K-steps sharing a head (head h = ks>>1). Combine math identical to the
// R3-verified attn_combine.
// ---------------------------------------------------------------------------
__global__ __launch_bounds__(256) void out_gemm(const _Float16* __restrict__ Op,
                                                const float* __restrict__ mlp,
                                                const short* __restrict__ Wt,
                                                const short* __restrict__ bias,
                                                void* __restrict__ outv,
                                                const int* __restrict__ flag)
{
    __shared__ short Als[2][2048];
    __shared__ short Bls[2][2048];

    const int tid = threadIdx.x;
    const int wave = tid >> 6, lane = tid & 63;
    const int quad = lane >> 4, l16 = lane & 15;
    const int m0 = blockIdx.x * 64;
    const int n0 = blockIdx.y * 64;

    f32x4 acc[4];
#pragma unroll
    for (int nt = 0; nt < 4; ++nt) {
        const float bv = bf2f(bias[n0 + nt*16 + l16]);
        acc[nt] = (f32x4){bv, bv, bv, bv};
    }

    const int row = tid >> 2, ch = (tid & 3) * 8;
    // X source: token m -> batch-head base + seq index (combine path)
    const int m = m0 + row;
    const int bhb = (m >> 11) * NHEADS;      // batch*NHEADS
    const int qq = m & (SEQ - 1);

#define OSTAGE(buf, k0) do { \
        const int cc = (k0) + ch; \
        const int h = cc >> 6, d = cc & 63; \
        const size_t r1 = (size_t)(bhb + h) * SEQ + qq; \
        const float2 ml1 = *(const float2*)&mlp[r1 * 2]; \
        const float2 ml2 = *(const float2*)&mlp[((size_t)(NBH * SEQ) + r1) * 2]; \
        const float M_ = fmaxf(ml1.x, ml2.x); \
        const float w1 = EXP2(ml1.x - M_) * ml1.y; \
        const float w2 = EXP2(ml2.x - M_) * ml2.y; \
        const float s_ = 1.0f / (w1 + w2); \
        const float f1 = w1 * s_, f2 = w2 * s_; \
        const half8 o1 = *(const half8*)&Op[r1 * HD + d]; \
        const half8 o2 = *(const half8*)&Op[(size_t)(NBH * SEQ) * HD + r1 * HD + d]; \
        short8 xb; \
        _Pragma("unroll") \
        for (int j = 0; j < 8; ++j) \
            xb[j] = f2bf(f1 * (float)o1[j] + f2 * (float)o2[j]); \
        *(short8*)&Als[buf][tid*8] = xb; \
        GLD16_OR_REG(buf, k0); \
    } while (0)
#ifdef HAS_GLD
#define GLD16_OR_REG(buf, k0) \
        GLD16(Wt + (size_t)(n0 + row) * D_MODEL + (k0) + ch, &Bls[buf][tid*8])
#else
#define GLD16_OR_REG(buf, k0) do { \
        short8 r1_ = *(const short8*)(Wt + (size_t)(n0 + row) * D_MODEL + (k0) + ch); \
        *(short8*)&Bls[buf][tid*8] = r1_; } while (0)
#endif

    OSTAGE(0, 0);
    __syncthreads();

#pragma unroll 2
    for (int ks = 0; ks < 24; ++ks) {
        const int cur = ks & 1;
        if (ks + 1 < 24) OSTAGE(cur ^ 1, (ks + 1) * 32);

        short8 a = *(const short8*)&Als[cur][(wave*16 + l16) * 32 + quad*8];
#pragma unroll
        for (int nt = 0; nt < 4; ++nt) {
            short8 b = *(const short8*)&Bls[cur][(nt*16 + l16) * 32 + quad*8];
            acc[nt] = __builtin_amdgcn_mfma_f32_16x16x32_bf16(a, b, acc[nt], 0, 0, 0);
        }
        __syncthreads();
    }
#undef OSTAGE
#undef GLD16_OR_REG

    const bool outf32 = (*flag != 0);
#pragma unroll
    for (int nt = 0; nt < 4; ++nt) {
        const int n = n0 + nt*16 + l16;
#pragma unroll
        for (int r = 0; r < 4; ++r) {
            const int mm = m0 + wave*16 + quad*4 + r;
            const size_t idx = (size_t)mm * D_MODEL + n;
            if (outf32) ((float*)outv)[idx] = acc[nt][r];
            else        ((short*)outv)[idx] = f2bf(acc[nt][r]);
        }
    }
}

// ---------------------------------------------------------------------------
// Flash attention R16 (unchanged from R5 - verified 48.4us, VGPR 72, no
// spill): 32 q/wave, 64-key tiles, KV-split x2, body order
// STAGE K(j+2),V(j+1) -> QK(j+1) -> PV(j) -> softmax(j+1) -> barrier.
// S transient within one body; P in per-wave LDS. Defer-max THR=8.
// LDS 48KB: K 2x8K, V 2x8K, P 4x4K. Grid 768 = 3/CU.
// ---------------------------------------------------------------------------
__global__ __launch_bounds__(256, 3) void attn_mfma(const short* __restrict__ q,
                                                    const short* __restrict__ k,
                                                    const _Float16* __restrict__ Vt,
                                                    _Float16* __restrict__ Op,
                                                    float* __restrict__ mlp)
{
    __shared__ __align__(16) short    Kls[2][4096];   // [8 dimchunk][64 key][8] bf16, 8KB/buf
    __shared__ __align__(16) _Float16 Vls[2][4096];   // [8 keychunk][64 dim][8] f16, 8KB/buf
    __shared__ __align__(16) _Float16 Pls[4][2048];   // per-wave [col][8 keychunk][16 q][8]

    const int tid  = threadIdx.x;
    const int wave = tid >> 6, lane = tid & 63;
    const int quad = lane >> 4, l16 = lane & 15;

    const int F = blockIdx.x;               // 768 = 8 xcd * 96
    const int xcd = F & 7, slot = F >> 3;   // slot 0..95
    const int bh = xcd * 3 + (slot >> 5);   // 3 heads per XCD (KV L2-resident)
    const int rem = slot & 31;
    const int q0 = (rem >> 1) * 128;        // 16 q-blocks of 128
    const int sp = rem & 1;                 // KV split index
    const int kb0 = sp * (SEQ / 2);
    const int b = bh / NHEADS, h = bh % NHEADS;
    const size_t bS = (size_t)b * SEQ;

    // two 16-q columns per wave
    short8 qf[2][2];
#pragma unroll
    for (int col = 0; col < 2; ++col)
#pragma unroll
    for (int k0h = 0; k0h < 2; ++k0h)
        qf[col][k0h] = *(const short8*)(q + (bS + q0 + wave*32 + col*16 + l16) * D_MODEL
                                          + h*HD + k0h*32 + quad*8);

    half8 ones;
#pragma unroll
    for (int j = 0; j < 8; ++j) ones[j] = (_Float16)1.0f;

    // staging: 512 16B-chunks per 8KB tile, 2 per thread, chunk-major layouts
    const int cK0 = tid >> 6,         keyK0 = tid & 63;      // slots 0..255
    const int cK1 = (tid + 256) >> 6, keyK1 = tid & 63;      // slots 256..511
    const short* kgp0 = k + (bS + kb0 + keyK0) * D_MODEL + h*HD + cK0*8;
    const short* kgp1 = k + (bS + kb0 + keyK1) * D_MODEL + h*HD + cK1*8;
    const _Float16* vgp0 = Vt + ((size_t)bh * HD + keyK0) * SEQ + kb0 + cK0*8;
    const _Float16* vgp1 = Vt + ((size_t)bh * HD + keyK1) * SEQ + kb0 + cK1*8;

#ifdef HAS_GLD
#define STAGE_K(buf, j0) do { \
        GLD16(kgp0 + (size_t)(j0) * D_MODEL, &Kls[buf][tid*8]); \
        GLD16(kgp1 + (size_t)(j0) * D_MODEL, &Kls[buf][(tid+256)*8]); \
    } while (0)
#define STAGE_V(buf, j0) do { \
        GLD16(vgp0 + (j0), &Vls[buf][tid*8]); \
        GLD16(vgp1 + (j0), &Vls[buf][(tid+256)*8]); \
    } while (0)
#else
#define STAGE_K(buf, j0) do { \
        short8 a_ = *(const short8*)(kgp0 + (size_t)(j0) * D_MODEL); \
        short8 b_ = *(const short8*)(kgp1 + (size_t)(j0) * D_MODEL); \
        *(short8*)&Kls[buf][tid*8] = a_;  *(short8*)&Kls[buf][(tid+256)*8] = b_; \
    } while (0)
#define STAGE_V(buf, j0) do { \
        half8 c_ = *(const half8*)(vgp0 + (j0)); \
        half8 d_ = *(const half8*)(vgp1 + (j0)); \
        *(half8*)&Vls[buf][tid*8] = c_;  *(half8*)&Vls[buf][(tid+256)*8] = d_; \
    } while (0)
#endif

    float m_ = -1e30f;
    f32x4 laccA = (f32x4){0.f,0.f,0.f,0.f}, laccB = (f32x4){0.f,0.f,0.f,0.f};
    f32x4 o[4][2];
#pragma unroll
    for (int t = 0; t < 4; ++t) { o[t][0] = (f32x4){0.f,0.f,0.f,0.f}; o[t][1] = (f32x4){0.f,0.f,0.f,0.f}; }

#define NT (SEQ / 2 / 64)   // 16 iterations over this split's keys

// QK^T of 64-key tile in K-buffer KB into transient logits S. One kf read
// feeds BOTH q-columns.
#define QK(S, KB) do { \
    _Pragma("unroll") \
    for (int t = 0; t < 4; ++t) { S[t][0] = (f32x4){0.f,0.f,0.f,0.f}; S[t][1] = (f32x4){0.f,0.f,0.f,0.f}; } \
    _Pragma("unroll") \
    for (int k0h = 0; k0h < 2; ++k0h) \
    _Pragma("unroll") \
    for (int t = 0; t < 4; ++t) { \
        short8 kf = *(const short8*)&Kls[KB][(k0h*4 + quad)*512 + (t*16 + l16)*8]; \
        S[t][0] = __builtin_amdgcn_mfma_f32_16x16x32_bf16(kf, qf[0][k0h], S[t][0], 0, 0, 0); \
        S[t][1] = __builtin_amdgcn_mfma_f32_16x16x32_bf16(kf, qf[1][k0h], S[t][1], 0, 0, 0); \
    } \
} while (0)

// PV of tile in V-buffer VB, P from per-wave Pls (written previous body)
#define PV(VB) do { \
    _Pragma("unroll") \
    for (int k0h = 0; k0h < 2; ++k0h) { \
        half8 pf0 = *(half8*)&Pls[wave][(k0h*4 + quad)*128 + l16*8]; \
        half8 pf1 = *(half8*)&Pls[wave][1024 + (k0h*4 + quad)*128 + l16*8]; \
        laccA = __builtin_amdgcn_mfma_f32_16x16x32_f16(ones, pf0, laccA, 0, 0, 0); \
        laccB = __builtin_amdgcn_mfma_f32_16x16x32_f16(ones, pf1, laccB, 0, 0, 0); \
        _Pragma("unroll") \
        for (int t = 0; t < 4; ++t) { \
            half8 vf = *(const half8*)&Vls[VB][(k0h*4 + quad)*512 + (t*16 + l16)*8]; \
            o[t][0] = __builtin_amdgcn_mfma_f32_16x16x32_f16(vf, pf0, o[t][0], 0, 0, 0); \
            o[t][1] = __builtin_amdgcn_mfma_f32_16x16x32_f16(vf, pf1, o[t][1], 0, 0, 0); \
        } \
    } \
} while (0)

// softmax on transient logits S: deferred max (THR=8, log2 domain), rescale
// o/lacc, pack P to f16, store to per-wave Pls (chunk-major).
#define SOFTMAX(S) do { \
    float mx = S[0][0][0]; \
    _Pragma("unroll") \
    for (int t = 0; t < 4; ++t) \
    _Pragma("unroll") \
    for (int c = 0; c < 2; ++c) \
    _Pragma("unroll") \
    for (int r = 0; r < 4; ++r) mx = fmaxf(mx, S[t][c][r]); \
    if (__any(mx > m_ + 8.f)) { \
        _Pragma("unroll") \
        for (int d = 1; d < 64; d <<= 1) mx = fmaxf(mx, __shfl_xor(mx, d)); \
        const float mn = fmaxf(m_, mx); \
        const float al = EXP2(m_ - mn); \
        _Pragma("unroll") \
        for (int t = 0; t < 4; ++t) \
        _Pragma("unroll") \
        for (int c = 0; c < 2; ++c) { \
            o[t][c][0] *= al; o[t][c][1] *= al; o[t][c][2] *= al; o[t][c][3] *= al; \
        } \
        laccA[0] *= al; laccB[0] *= al; \
        m_ = mn; \
    } \
    _Pragma("unroll") \
    for (int t = 0; t < 4; ++t) \
    _Pragma("unroll") \
    for (int c = 0; c < 2; ++c) { \
        union { fp16x2 h2[2]; int2 v; } u4; \
        u4.h2[0] = PKF16(EXP2(S[t][c][0] - m_), EXP2(S[t][c][1] - m_)); \
        u4.h2[1] = PKF16(EXP2(S[t][c][2] - m_), EXP2(S[t][c][3] - m_)); \
        const int kc = 2*t + (quad >> 1); \
        *(int2*)&Pls[wave][c*1024 + kc*128 + l16*8 + (quad & 1)*4] = u4.v; \
    } \
} while (0)

// One iteration: stage K(j+2) & V(j+1); QK(j+1); PV(j); softmax(j+1); barrier
#define BODY(JT) do { \
    if ((JT) + 2 < NT) STAGE_K(((JT) + 2) & 1, ((JT) + 2) * 64); \
    if ((JT) + 1 < NT) STAGE_V(((JT) + 1) & 1, ((JT) + 1) * 64); \
    f32x4 s_[4][2]; \
    __builtin_amdgcn_s_setprio(1); \
    if ((JT) + 1 < NT) QK(s_, ((JT) + 1) & 1); \
    PV((JT) & 1); \
    __builtin_amdgcn_s_setprio(0); \
    if ((JT) + 1 < NT) SOFTMAX(s_); \
    __syncthreads(); \
} while (0)

    // ---- prologue: K0,V0 staged+drained; K1 staged; QK(0)+softmax(0) ----
    STAGE_K(0, 0); STAGE_V(0, 0);
    __syncthreads();
    STAGE_K(1, 64);
    {
        f32x4 s_[4][2];
        QK(s_, 0);
        SOFTMAX(s_);     // P(0) -> Pls
    }
    __syncthreads();     // drains STAGE_K(1)

    for (int jt = 0; jt < NT; ++jt) BODY(jt);

    // ---- normalized f16 partials + (m, l) per column ----
#pragma unroll
    for (int col = 0; col < 2; ++col) {
        const f32x4 la = col ? laccB : laccA;
        const float inv = 1.0f / la[0];
        const int myq = q0 + wave*32 + col*16 + l16;
        const size_t prow = ((size_t)sp * (NBH * SEQ) + (size_t)bh * SEQ + myq);
        _Float16* orow = Op + prow * HD;
#pragma unroll
        for (int t = 0; t < 4; ++t) {
            union { _Float16 h4[4]; int2 v; } u4;
#pragma unroll
            for (int r = 0; r < 4; ++r) u4.h4[r] = (_Float16)(o[t][col][r] * inv);
            *(int2*)(orow + t*16 + quad*4) = u4.v;
        }
        if (quad == 0) {
            float2 mlv; mlv.x = m_; mlv.y = la[0];
            *(float2*)&mlp[prow * 2] = mlv;
        }
    }
#undef BODY
#undef SOFTMAX
#undef PV
#undef QK
#undef NT
#undef STAGE_K
#undef STAGE_V
}

// ---------------------------------------------------------------------------
extern "C" void kernel_launch(void* const* d_in, const int* in_sizes, int n_in,
                              void* d_out, int out_size, void* d_ws, size_t ws_size,
                              hipStream_t stream)
{
    int* flag = (int*)d_ws;
    short* xc = (short*)((char*)d_ws + 64);
    short* Wt = xc + NX;                 // 4 transposed weights q|k|v|o
    short* bc = Wt + 4 * NW;             // biases q|k|v|o
    short* qb = bc + 4 * D_MODEL;
    short* kb = qb + NX;
    _Float16* Vt = (_Float16*)(kb + NX); // [24][64][2048] f16
    _Float16* Op = (_Float16*)(Vt + NX); // 2 x [24][2048][64] f16 partials
    float* mlp = (float*)(Op + (size_t)2 * NBH * SEQ * HD);  // 2 x [24][2048] (m,l)

    fused_conv<<<3649, 256, 0, stream>>>(d_in[0],
                                         d_in[1], d_in[3], d_in[5], d_in[7],
                                         d_in[2], d_in[4], d_in[6], d_in[8],
                                         xc, Wt, bc, flag);

    qkv_gemm<<<dim3(NTOK/64, 2304/128), 256, 0, stream>>>(xc, Wt, bc, qb, kb, Vt);

    attn_mfma<<<768, 256, 0, stream>>>(qb, kb, Vt, Op, mlp);

    out_gemm<<<dim3(NTOK/64, D_MODEL/64), 256, 0, stream>>>(Op, mlp, Wt + 3*NW, bc + 3*D_MODEL, d_out, flag);
}

// Round 7
// 169.752 us; speedup vs baseline: 1.0333x; 1.0333x over previous
//
#include <hip/hip_runtime.h>
#include <hip/hip_bf16.h>
#include <hip/hip_fp16.h>

#define D_MODEL 768
#define NHEADS  12
#define HD      64
#define BATCH   2
#define SEQ     2048
#define NTOK    (BATCH*SEQ)   // 4096
#define NX      ((size_t)NTOK * D_MODEL)     // 3,145,728
#define NW      ((size_t)D_MODEL * D_MODEL)  // 589,824
#define NBH     (BATCH*NHEADS)               // 24
#define SC_LOG2 0.18033688f   // (1/8) * log2(e), folded into Wq/bq

typedef __attribute__((ext_vector_type(8))) short    short8;
typedef __attribute__((ext_vector_type(8))) _Float16 half8;
typedef __attribute__((ext_vector_type(2))) __fp16   fp16x2;
typedef __attribute__((ext_vector_type(4))) float    f32x4;

__device__ __forceinline__ float bf2f(short s) {
    union { unsigned u; float f; } c;
    c.u = ((unsigned)(unsigned short)s) << 16;
    return c.f;
}
__device__ __forceinline__ short f2bf(float f) {
    __hip_bfloat16 h = __float2bfloat16(f);
    return *(short*)&h;
}

#ifdef __has_builtin
#if __has_builtin(__builtin_amdgcn_global_load_lds)
#define HAS_GLD 1
#endif
#if __has_builtin(__builtin_amdgcn_exp2f)
#define EXP2(x) __builtin_amdgcn_exp2f(x)
#else
#define EXP2(x) exp2f(x)
#endif
#if __has_builtin(__builtin_amdgcn_cvt_pkrtz)
#define HAS_PKRTZ 1
#endif
#else
#define EXP2(x) exp2f(x)
#endif
#ifdef HAS_GLD
#define GLD16(gp, lp) __builtin_amdgcn_global_load_lds( \
    (const __attribute__((address_space(1))) void*)(gp), \
    (__attribute__((address_space(3))) void*)(lp), 16, 0, 0)
#endif

#ifdef HAS_PKRTZ
#define PKF16(a, b) __builtin_amdgcn_cvt_pkrtz((a), (b))
#else
#define PKF16(a, b) ((fp16x2){ (__fp16)(a), (__fp16)(b) })
#endif

// ---------------------------------------------------------------------------
// Fused conversion kernel (one launch): every block locally detects the input
// dtype from x's first 4096 halfwords, then converts its assigned slice.
// ---------------------------------------------------------------------------
__global__ __launch_bounds__(256) void fused_conv(
        const void* __restrict__ xin,
        const void* __restrict__ w0, const void* __restrict__ w1,
        const void* __restrict__ w2, const void* __restrict__ w3,
        const void* __restrict__ b0, const void* __restrict__ b1,
        const void* __restrict__ b2, const void* __restrict__ b3,
        short* __restrict__ xc, short* __restrict__ wt,
        short* __restrict__ bc, int* __restrict__ flag)
{
    __shared__ int red[256];
    __shared__ float T[64][65];
    const int tid = threadIdx.x;
    const int F = blockIdx.x;

    {
        const short* xs = (const short*)xin;
        int maxe = 0;
#pragma unroll
        for (int u = 0; u < 16; ++u) {
            int e = ((unsigned short)xs[tid * 16 + u] >> 7) & 0xFF;
            maxe = max(maxe, e);
        }
        red[tid] = maxe;
        __syncthreads();
        for (int s = 128; s > 0; s >>= 1) {
            if (tid < s) red[tid] = max(red[tid], red[tid + s]);
            __syncthreads();
        }
    }
    const bool isf = (red[0] > 140);

    if (F < 3072) {
        const int i = F * 256 + tid;
        if (isf) {
            float4 f = ((const float4*)xin)[i];
            short4 o = { f2bf(f.x), f2bf(f.y), f2bf(f.z), f2bf(f.w) };
            ((short4*)xc)[i] = o;
        } else {
            ((short4*)xc)[i] = ((const short4*)xin)[i];
        }
    } else if (F < 3648) {
        const int G = F - 3072;
        const int z = G / 144, rr = G % 144;
        const int k0 = (rr % 12) * 64, n0 = (rr / 12) * 64;
        const void* src = (z == 0) ? w0 : (z == 1) ? w1 : (z == 2) ? w2 : w3;
        const float sc = (z == 0) ? SC_LOG2 : 1.0f;
        const int la = tid & 15, lb = tid >> 4;
#pragma unroll
        for (int u = 0; u < 4; ++u) {
            const int kr = (lb & 3) + 4 * u + 16 * (lb >> 2);
            if (isf) {
                float4 f = *(const float4*)((const float*)src + (size_t)(k0 + kr) * D_MODEL + n0 + la * 4);
                T[kr][la*4+0] = f.x; T[kr][la*4+1] = f.y; T[kr][la*4+2] = f.z; T[kr][la*4+3] = f.w;
            } else {
                short4 s = *(const short4*)((const short*)src + (size_t)(k0 + kr) * D_MODEL + n0 + la * 4);
                T[kr][la*4+0] = bf2f(s.x); T[kr][la*4+1] = bf2f(s.y);
                T[kr][la*4+2] = bf2f(s.z); T[kr][la*4+3] = bf2f(s.w);
            }
        }
        __syncthreads();
#pragma unroll
        for (int u = 0; u < 4; ++u) {
            const int nr = (lb & 3) + 4 * u + 16 * (lb >> 2);
            short4 o = { f2bf(T[la*4+0][nr] * sc), f2bf(T[la*4+1][nr] * sc),
                         f2bf(T[la*4+2][nr] * sc), f2bf(T[la*4+3][nr] * sc) };
            *(short4*)(wt + (size_t)z * NW + (size_t)(n0 + nr) * D_MODEL + k0 + la * 4) = o;
        }
    } else {
        if (tid == 0) *flag = isf ? 1 : 0;
        const void* srcs[4] = { b0, b1, b2, b3 };
        for (int z = 0; z < 4; ++z) {
            const float sc = (z == 0) ? SC_LOG2 : 1.0f;
            for (int i = tid; i < D_MODEL; i += 256) {
                float v = isf ? ((const float*)srcs[z])[i] : bf2f(((const short*)srcs[z])[i]);
                bc[z * D_MODEL + i] = f2bf(v * sc);
            }
        }
    }
}

// ---------------------------------------------------------------------------
// Fused QKV GEMM R18: 128M x 128N tiles, 512 threads / 8 waves (4M x 2N),
// wave = 32M x 64N. Ladder step 64->128 tile (m92->m97: 343->874 TF): staging
// efficiency 2.67 -> 4 MFMA/KB, 64 MFMA per block-iter, 18 waves/CU.
// Grid (32,18) = 576 blocks. Double-buffered GLD16, BK=32, 24 K-steps.
// V segment -> Vt f16 [bh][dim][SEQ] via TWO 64-token LDS transpose passes
// (T = 128 dims x 72 pitch overlays the staging buffers).
// ---------------------------------------------------------------------------
__global__ __launch_bounds__(512) void qkv_gemm(const short* __restrict__ X,
                                                const short* __restrict__ Wt,
                                                const short* __restrict__ bias,
                                                short* __restrict__ qb,
                                                short* __restrict__ kb,
                                                _Float16* __restrict__ Vt)
{
    __shared__ __align__(16) char shbuf[32768];
    short* Als = (short*)shbuf;               // [2][4096] = 128 rows x 32
    short* Bls = (short*)(shbuf + 16384);     // [2][4096]
    _Float16* T = (_Float16*)shbuf;           // epilogue: 128*72 f16 = 18432 B

    const int tid = threadIdx.x;
    const int wave = tid >> 6, lane = tid & 63;
    const int quad = lane >> 4, l16 = lane & 15;
    const int wm = wave & 3, wn = wave >> 2;
    const int m0 = blockIdx.x * 128;
    const int ng = blockIdx.y * 128;

    f32x4 acc[2][4];
#pragma unroll
    for (int nt = 0; nt < 4; ++nt) {
        const float bv = bf2f(bias[ng + wn*64 + nt*16 + l16]);
#pragma unroll
        for (int mt = 0; mt < 2; ++mt) acc[mt][nt] = (f32x4){bv, bv, bv, bv};
    }

    const int row = tid >> 2, ch = (tid & 3) * 8;   // row 0..127, ch 0/8/16/24
#ifdef HAS_GLD
#define QSTAGE(buf, k0) do { \
        GLD16(X  + (size_t)(m0 + row) * D_MODEL + (k0) + ch, &Als[(buf)*4096 + tid*8]); \
        GLD16(Wt + (size_t)(ng + row) * D_MODEL + (k0) + ch, &Bls[(buf)*4096 + tid*8]); \
    } while (0)
#else
#define QSTAGE(buf, k0) do { \
        short8 r0 = *(const short8*)(X  + (size_t)(m0 + row) * D_MODEL + (k0) + ch); \
        short8 r1 = *(const short8*)(Wt + (size_t)(ng + row) * D_MODEL + (k0) + ch); \
        *(short8*)&Als[(buf)*4096 + tid*8] = r0; \
        *(short8*)&Bls[(buf)*4096 + tid*8] = r1; \
    } while (0)
#endif

    QSTAGE(0, 0);
    __syncthreads();

    for (int ks = 0; ks < 24; ++ks) {
        const int cur = ks & 1;
        if (ks + 1 < 24) QSTAGE(cur ^ 1, (ks + 1) * 32);

        short8 a[2], b[4];
#pragma unroll
        for (int mt = 0; mt < 2; ++mt)
            a[mt] = *(const short8*)&Als[cur*4096 + (wm*32 + mt*16 + l16) * 32 + quad*8];
#pragma unroll
        for (int nt = 0; nt < 4; ++nt)
            b[nt] = *(const short8*)&Bls[cur*4096 + (wn*64 + nt*16 + l16) * 32 + quad*8];
#pragma unroll
        for (int mt = 0; mt < 2; ++mt)
#pragma unroll
        for (int nt = 0; nt < 4; ++nt)
            acc[mt][nt] = __builtin_amdgcn_mfma_f32_16x16x32_bf16(a[mt], b[nt], acc[mt][nt], 0, 0, 0);

        __syncthreads();
    }
#undef QSTAGE

    const int seg = blockIdx.y / 6;   // 0=q, 1=k, 2=v
    if (seg < 2) {
        short* out = seg ? kb : qb;
        const int nl = ng - seg * 768;
#pragma unroll
        for (int mt = 0; mt < 2; ++mt)
#pragma unroll
        for (int nt = 0; nt < 4; ++nt) {
            const int n = nl + wn*64 + nt*16 + l16;
#pragma unroll
            for (int r = 0; r < 4; ++r) {
                const int m = m0 + wm*32 + mt*16 + quad*4 + r;
                out[(size_t)m * D_MODEL + n] = f2bf(acc[mt][nt][r]);
            }
        }
    } else {
        // two-pass LDS transpose: pass p handles tokens [p*64, p*64+64)
        const int batch = m0 >> 11, tokb0 = m0 & (SEQ - 1);
#pragma unroll
        for (int p = 0; p < 2; ++p) {
            if ((wm >> 1) == p) {
#pragma unroll
                for (int nt = 0; nt < 4; ++nt) {
                    const int dim_l = wn*64 + nt*16 + l16;
#pragma unroll
                    for (int mt = 0; mt < 2; ++mt) {
                        const int tok_l = (wm & 1)*32 + mt*16 + quad*4;
                        union { _Float16 h4[4]; int2 v; } u;
#pragma unroll
                        for (int r = 0; r < 4; ++r) u.h4[r] = (_Float16)acc[mt][nt][r];
                        *(int2*)&T[dim_l * 72 + tok_l] = u.v;
                    }
                }
            }
            __syncthreads();
#pragma unroll
            for (int u = 0; u < 2; ++u) {
                const int slot = tid + u * 512;        // 0..1023 = 128 dims x 8 chunks
                const int drow = slot >> 3, chk = slot & 7;
                int4 val = *(const int4*)&T[drow * 72 + chk * 8];
                const int dim_g = ng - 1536 + drow;
                const int h = dim_g >> 6, d = dim_g & 63;
                *(int4*)(Vt + ((size_t)(batch * NHEADS + h) * HD + d) * SEQ
                              + tokb0 + p*64 + chk*8) = val;
            }
            if (p == 0) __syncthreads();   // T reused by pass 1
        }
    }
}

// ---------------------------------------------------------------------------
// Output projection R18: fused combine with T14 async split. The ks+1 partial
// loads (Op x2 + (m,l) x2) are issued into named registers BEFORE the MFMA
// block and converted/ds_written AFTER it, so HBM latency hides under the
// MFMA+ds_read phase (R6 did the combine synchronously between barriers and
// absorbed the old combine kernel's full cost). Combine math = R3-verified.
// ---------------------------------------------------------------------------
__global__ __launch_bounds__(256) void out_gemm(const _Float16* __restrict__ Op,
                                                const float* __restrict__ mlp,
                                                const short* __restrict__ Wt,
                                                const short* __restrict__ bias,
                                                void* __restrict__ outv,
                                                const int* __restrict__ flag)
{
    __shared__ short Als[2][2048];
    __shared__ short Bls[2][2048];

    const int tid = threadIdx.x;
    const int wave = tid >> 6, lane = tid & 63;
    const int quad = lane >> 4, l16 = lane & 15;
    const int m0 = blockIdx.x * 64;
    const int n0 = blockIdx.y * 64;

    f32x4 acc[4];
#pragma unroll
    for (int nt = 0; nt < 4; ++nt) {
        const float bv = bf2f(bias[n0 + nt*16 + l16]);
        acc[nt] = (f32x4){bv, bv, bv, bv};
    }

    const int row = tid >> 2, ch = (tid & 3) * 8;
    const int m = m0 + row;
    const int bhb = (m >> 11) * NHEADS;      // batch * NHEADS
    const int qq = m & (SEQ - 1);
    const _Float16* Op2 = Op + (size_t)(NBH * SEQ) * HD;

#define XLOAD(ks) do { \
        const int cc = (ks) * 32 + ch; \
        const int h = cc >> 6, d = cc & 63; \
        const size_t r1 = (size_t)(bhb + h) * SEQ + qq; \
        const float2 ml1 = *(const float2*)&mlp[r1 * 2]; \
        const float2 ml2 = *(const float2*)&mlp[((size_t)(NBH * SEQ) + r1) * 2]; \
        p1 = *(const half8*)&Op[r1 * HD + d]; \
        p2 = *(const half8*)&Op2[r1 * HD + d]; \
        const float M_ = fmaxf(ml1.x, ml2.x); \
        const float w1 = EXP2(ml1.x - M_) * ml1.y; \
        const float w2 = EXP2(ml2.x - M_) * ml2.y; \
        const float s_ = 1.0f / (w1 + w2); \
        f1 = w1 * s_; f2 = w2 * s_; \
    } while (0)

#define XSTORE(buf) do { \
        short8 xb; \
        _Pragma("unroll") \
        for (int j = 0; j < 8; ++j) \
            xb[j] = f2bf(f1 * (float)p1[j] + f2 * (float)p2[j]); \
        *(short8*)&Als[buf][tid*8] = xb; \
    } while (0)

#ifdef HAS_GLD
#define BSTAGE(buf, k0) \
        GLD16(Wt + (size_t)(n0 + row) * D_MODEL + (k0) + ch, &Bls[buf][tid*8])
#else
#define BSTAGE(buf, k0) do { \
        short8 r1_ = *(const short8*)(Wt + (size_t)(n0 + row) * D_MODEL + (k0) + ch); \
        *(short8*)&Bls[buf][tid*8] = r1_; } while (0)
#endif

    half8 p1, p2; float f1, f2;
    XLOAD(0); XSTORE(0);
    BSTAGE(0, 0);
    __syncthreads();

    for (int ks = 0; ks < 24; ++ks) {
        const int cur = ks & 1;
        if (ks + 1 < 24) {
            XLOAD(ks + 1);             // issue loads early (T14)
            BSTAGE(cur ^ 1, (ks + 1) * 32);
        }

        short8 a = *(const short8*)&Als[cur][(wave*16 + l16) * 32 + quad*8];
#pragma unroll
        for (int nt = 0; nt < 4; ++nt) {
            short8 b = *(const short8*)&Bls[cur][(nt*16 + l16) * 32 + quad*8];
            acc[nt] = __builtin_amdgcn_mfma_f32_16x16x32_bf16(a, b, acc[nt], 0, 0, 0);
        }

        if (ks + 1 < 24) XSTORE(cur ^ 1);   // convert + LDS write late
        __syncthreads();
    }
#undef XLOAD
#undef XSTORE
#undef BSTAGE

    const bool outf32 = (*flag != 0);
#pragma unroll
    for (int nt = 0; nt < 4; ++nt) {
        const int n = n0 + nt*16 + l16;
#pragma unroll
        for (int r = 0; r < 4; ++r) {
            const int mm = m0 + wave*16 + quad*4 + r;
            const size_t idx = (size_t)mm * D_MODEL + n;
            if (outf32) ((float*)outv)[idx] = acc[nt][r];
            else        ((short*)outv)[idx] = f2bf(acc[nt][r]);
        }
    }
}

// ---------------------------------------------------------------------------
// Flash attention R16 (unchanged - verified twice, ~47us, VGPR 72, no spill):
// 32 q/wave, 64-key tiles, KV-split x2, body order
// STAGE K(j+2),V(j+1) -> QK(j+1) -> PV(j) -> softmax(j+1) -> barrier.
// S transient within one body; P in per-wave LDS. Defer-max THR=8.
// LDS 48KB: K 2x8K, V 2x8K, P 4x4K. Grid 768 = 3/CU.
// ---------------------------------------------------------------------------
__global__ __launch_bounds__(256, 3) void attn_mfma(const short* __restrict__ q,
                                                    const short* __restrict__ k,
                                                    const _Float16* __restrict__ Vt,
                                                    _Float16* __restrict__ Op,
                                                    float* __restrict__ mlp)
{
    __shared__ __align__(16) short    Kls[2][4096];   // [8 dimchunk][64 key][8] bf16, 8KB/buf
    __shared__ __align__(16) _Float16 Vls[2][4096];   // [8 keychunk][64 dim][8] f16, 8KB/buf
    __shared__ __align__(16) _Float16 Pls[4][2048];   // per-wave [col][8 keychunk][16 q][8]

    const int tid  = threadIdx.x;
    const int wave = tid >> 6, lane = tid & 63;
    const int quad = lane >> 4, l16 = lane & 15;

    const int F = blockIdx.x;               // 768 = 8 xcd * 96
    const int xcd = F & 7, slot = F >> 3;   // slot 0..95
    const int bh = xcd * 3 + (slot >> 5);   // 3 heads per XCD (KV L2-resident)
    const int rem = slot & 31;
    const int q0 = (rem >> 1) * 128;        // 16 q-blocks of 128
    const int sp = rem & 1;                 // KV split index
    const int kb0 = sp * (SEQ / 2);
    const int b = bh / NHEADS, h = bh % NHEADS;
    const size_t bS = (size_t)b * SEQ;

    // two 16-q columns per wave
    short8 qf[2][2];
#pragma unroll
    for (int col = 0; col < 2; ++col)
#pragma unroll
    for (int k0h = 0; k0h < 2; ++k0h)
        qf[col][k0h] = *(const short8*)(q + (bS + q0 + wave*32 + col*16 + l16) * D_MODEL
                                          + h*HD + k0h*32 + quad*8);

    half8 ones;
#pragma unroll
    for (int j = 0; j < 8; ++j) ones[j] = (_Float16)1.0f;

    // staging: 512 16B-chunks per 8KB tile, 2 per thread, chunk-major layouts
    const int cK0 = tid >> 6,         keyK0 = tid & 63;      // slots 0..255
    const int cK1 = (tid + 256) >> 6, keyK1 = tid & 63;      // slots 256..511
    const short* kgp0 = k + (bS + kb0 + keyK0) * D_MODEL + h*HD + cK0*8;
    const short* kgp1 = k + (bS + kb0 + keyK1) * D_MODEL + h*HD + cK1*8;
    const _Float16* vgp0 = Vt + ((size_t)bh * HD + keyK0) * SEQ + kb0 + cK0*8;
    const _Float16* vgp1 = Vt + ((size_t)bh * HD + keyK1) * SEQ + kb0 + cK1*8;

#ifdef HAS_GLD
#define STAGE_K(buf, j0) do { \
        GLD16(kgp0 + (size_t)(j0) * D_MODEL, &Kls[buf][tid*8]); \
        GLD16(kgp1 + (size_t)(j0) * D_MODEL, &Kls[buf][(tid+256)*8]); \
    } while (0)
#define STAGE_V(buf, j0) do { \
        GLD16(vgp0 + (j0), &Vls[buf][tid*8]); \
        GLD16(vgp1 + (j0), &Vls[buf][(tid+256)*8]); \
    } while (0)
#else
#define STAGE_K(buf, j0) do { \
        short8 a_ = *(const short8*)(kgp0 + (size_t)(j0) * D_MODEL); \
        short8 b_ = *(const short8*)(kgp1 + (size_t)(j0) * D_MODEL); \
        *(short8*)&Kls[buf][tid*8] = a_;  *(short8*)&Kls[buf][(tid+256)*8] = b_; \
    } while (0)
#define STAGE_V(buf, j0) do { \
        half8 c_ = *(const half8*)(vgp0 + (j0)); \
        half8 d_ = *(const half8*)(vgp1 + (j0)); \
        *(half8*)&Vls[buf][tid*8] = c_;  *(half8*)&Vls[buf][(tid+256)*8] = d_; \
    } while (0)
#endif

    float m_ = -1e30f;
    f32x4 laccA = (f32x4){0.f,0.f,0.f,0.f}, laccB = (f32x4){0.f,0.f,0.f,0.f};
    f32x4 o[4][2];
#pragma unroll
    for (int t = 0; t < 4; ++t) { o[t][0] = (f32x4){0.f,0.f,0.f,0.f}; o[t][1] = (f32x4){0.f,0.f,0.f,0.f}; }

#define NT (SEQ / 2 / 64)   // 16 iterations over this split's keys

// QK^T of 64-key tile in K-buffer KB into transient logits S. One kf read
// feeds BOTH q-columns.
#define QK(S, KB) do { \
    _Pragma("unroll") \
    for (int t = 0; t < 4; ++t) { S[t][0] = (f32x4){0.f,0.f,0.f,0.f}; S[t][1] = (f32x4){0.f,0.f,0.f,0.f}; } \
    _Pragma("unroll") \
    for (int k0h = 0; k0h < 2; ++k0h) \
    _Pragma("unroll") \
    for (int t = 0; t < 4; ++t) { \
        short8 kf = *(const short8*)&Kls[KB][(k0h*4 + quad)*512 + (t*16 + l16)*8]; \
        S[t][0] = __builtin_amdgcn_mfma_f32_16x16x32_bf16(kf, qf[0][k0h], S[t][0], 0, 0, 0); \
        S[t][1] = __builtin_amdgcn_mfma_f32_16x16x32_bf16(kf, qf[1][k0h], S[t][1], 0, 0, 0); \
    } \
} while (0)

// PV of tile in V-buffer VB, P from per-wave Pls (written previous body)
#define PV(VB) do { \
    _Pragma("unroll") \
    for (int k0h = 0; k0h < 2; ++k0h) { \
        half8 pf0 = *(half8*)&Pls[wave][(k0h*4 + quad)*128 + l16*8]; \
        half8 pf1 = *(half8*)&Pls[wave][1024 + (k0h*4 + quad)*128 + l16*8]; \
        laccA = __builtin_amdgcn_mfma_f32_16x16x32_f16(ones, pf0, laccA, 0, 0, 0); \
        laccB = __builtin_amdgcn_mfma_f32_16x16x32_f16(ones, pf1, laccB, 0, 0, 0); \
        _Pragma("unroll") \
        for (int t = 0; t < 4; ++t) { \
            half8 vf = *(const half8*)&Vls[VB][(k0h*4 + quad)*512 + (t*16 + l16)*8]; \
            o[t][0] = __builtin_amdgcn_mfma_f32_16x16x32_f16(vf, pf0, o[t][0], 0, 0, 0); \
            o[t][1] = __builtin_amdgcn_mfma_f32_16x16x32_f16(vf, pf1, o[t][1], 0, 0, 0); \
        } \
    } \
} while (0)

// softmax on transient logits S: deferred max (THR=8, log2 domain), rescale
// o/lacc, pack P to f16, store to per-wave Pls (chunk-major).
#define SOFTMAX(S) do { \
    float mx = S[0][0][0]; \
    _Pragma("unroll") \
    for (int t = 0; t < 4; ++t) \
    _Pragma("unroll") \
    for (int c = 0; c < 2; ++c) \
    _Pragma("unroll") \
    for (int r = 0; r < 4; ++r) mx = fmaxf(mx, S[t][c][r]); \
    if (__any(mx > m_ + 8.f)) { \
        _Pragma("unroll") \
        for (int d = 1; d < 64; d <<= 1) mx = fmaxf(mx, __shfl_xor(mx, d)); \
        const float mn = fmaxf(m_, mx); \
        const float al = EXP2(m_ - mn); \
        _Pragma("unroll") \
        for (int t = 0; t < 4; ++t) \
        _Pragma("unroll") \
        for (int c = 0; c < 2; ++c) { \
            o[t][c][0] *= al; o[t][c][1] *= al; o[t][c][2] *= al; o[t][c][3] *= al; \
        } \
        laccA[0] *= al; laccB[0] *= al; \
        m_ = mn; \
    } \
    _Pragma("unroll") \
    for (int t = 0; t < 4; ++t) \
    _Pragma("unroll") \
    for (int c = 0; c < 2; ++c) { \
        union { fp16x2 h2[2]; int2 v; } u4; \
        u4.h2[0] = PKF16(EXP2(S[t][c][0] - m_), EXP2(S[t][c][1] - m_)); \
        u4.h2[1] = PKF16(EXP2(S[t][c][2] - m_), EXP2(S[t][c][3] - m_)); \
        const int kc = 2*t + (quad >> 1); \
        *(int2*)&Pls[wave][c*1024 + kc*128 + l16*8 + (quad & 1)*4] = u4.v; \
    } \
} while (0)

// One iteration: stage K(j+2) & V(j+1); QK(j+1); PV(j); softmax(j+1); barrier
#define BODY(JT) do { \
    if ((JT) + 2 < NT) STAGE_K(((JT) + 2) & 1, ((JT) + 2) * 64); \
    if ((JT) + 1 < NT) STAGE_V(((JT) + 1) & 1, ((JT) + 1) * 64); \
    f32x4 s_[4][2]; \
    __builtin_amdgcn_s_setprio(1); \
    if ((JT) + 1 < NT) QK(s_, ((JT) + 1) & 1); \
    PV((JT) & 1); \
    __builtin_amdgcn_s_setprio(0); \
    if ((JT) + 1 < NT) SOFTMAX(s_); \
    __syncthreads(); \
} while (0)

    // ---- prologue: K0,V0 staged+drained; K1 staged; QK(0)+softmax(0) ----
    STAGE_K(0, 0); STAGE_V(0, 0);
    __syncthreads();
    STAGE_K(1, 64);
    {
        f32x4 s_[4][2];
        QK(s_, 0);
        SOFTMAX(s_);     // P(0) -> Pls
    }
    __syncthreads();     // drains STAGE_K(1)

    for (int jt = 0; jt < NT; ++jt) BODY(jt);

    // ---- normalized f16 partials + (m, l) per column ----
#pragma unroll
    for (int col = 0; col < 2; ++col) {
        const f32x4 la = col ? laccB : laccA;
        const float inv = 1.0f / la[0];
        const int myq = q0 + wave*32 + col*16 + l16;
        const size_t prow = ((size_t)sp * (NBH * SEQ) + (size_t)bh * SEQ + myq);
        _Float16* orow = Op + prow * HD;
#pragma unroll
        for (int t = 0; t < 4; ++t) {
            union { _Float16 h4[4]; int2 v; } u4;
#pragma unroll
            for (int r = 0; r < 4; ++r) u4.h4[r] = (_Float16)(o[t][col][r] * inv);
            *(int2*)(orow + t*16 + quad*4) = u4.v;
        }
        if (quad == 0) {
            float2 mlv; mlv.x = m_; mlv.y = la[0];
            *(float2*)&mlp[prow * 2] = mlv;
        }
    }
#undef BODY
#undef SOFTMAX
#undef PV
#undef QK
#undef NT
#undef STAGE_K
#undef STAGE_V
}

// ---------------------------------------------------------------------------
extern "C" void kernel_launch(void* const* d_in, const int* in_sizes, int n_in,
                              void* d_out, int out_size, void* d_ws, size_t ws_size,
                              hipStream_t stream)
{
    int* flag = (int*)d_ws;
    short* xc = (short*)((char*)d_ws + 64);
    short* Wt = xc + NX;                 // 4 transposed weights q|k|v|o
    short* bc = Wt + 4 * NW;             // biases q|k|v|o
    short* qb = bc + 4 * D_MODEL;
    short* kb = qb + NX;
    _Float16* Vt = (_Float16*)(kb + NX); // [24][64][2048] f16
    _Float16* Op = (_Float16*)(Vt + NX); // 2 x [24][2048][64] f16 partials
    float* mlp = (float*)(Op + (size_t)2 * NBH * SEQ * HD);  // 2 x [24][2048] (m,l)

    fused_conv<<<3649, 256, 0, stream>>>(d_in[0],
                                         d_in[1], d_in[3], d_in[5], d_in[7],
                                         d_in[2], d_in[4], d_in[6], d_in[8],
                                         xc, Wt, bc, flag);

    qkv_gemm<<<dim3(NTOK/128, 2304/128), 512, 0, stream>>>(xc, Wt, bc, qb, kb, Vt);

    attn_mfma<<<768, 256, 0, stream>>>(qb, kb, Vt, Op, mlp);

    out_gemm<<<dim3(NTOK/64, D_MODEL/64), 256, 0, stream>>>(Op, mlp, Wt + 3*NW, bc + 3*D_MODEL, d_out, flag);
}

// Round 8
// 166.218 us; speedup vs baseline: 1.0553x; 1.0213x over previous
//
#include <hip/hip_runtime.h>
#include <hip/hip_bf16.h>
#include <hip/hip_fp16.h>

#define D_MODEL 768
#define NHEADS  12
#define HD      64
#define BATCH   2
#define SEQ     2048
#define NTOK    (BATCH*SEQ)   // 4096
#define NX      ((size_t)NTOK * D_MODEL)     // 3,145,728
#define NW      ((size_t)D_MODEL * D_MODEL)  // 589,824
#define NBH     (BATCH*NHEADS)               // 24
#define SC_LOG2 0.18033688f   // (1/8) * log2(e), folded into Wq/bq

typedef __attribute__((ext_vector_type(8))) short    short8;
typedef __attribute__((ext_vector_type(8))) _Float16 half8;
typedef __attribute__((ext_vector_type(2))) __fp16   fp16x2;
typedef __attribute__((ext_vector_type(4))) float    f32x4;

__device__ __forceinline__ float bf2f(short s) {
    union { unsigned u; float f; } c;
    c.u = ((unsigned)(unsigned short)s) << 16;
    return c.f;
}
__device__ __forceinline__ short f2bf(float f) {
    __hip_bfloat16 h = __float2bfloat16(f);
    return *(short*)&h;
}

#ifdef __has_builtin
#if __has_builtin(__builtin_amdgcn_global_load_lds)
#define HAS_GLD 1
#endif
#if __has_builtin(__builtin_amdgcn_exp2f)
#define EXP2(x) __builtin_amdgcn_exp2f(x)
#else
#define EXP2(x) exp2f(x)
#endif
#if __has_builtin(__builtin_amdgcn_cvt_pkrtz)
#define HAS_PKRTZ 1
#endif
#else
#define EXP2(x) exp2f(x)
#endif
#ifdef HAS_GLD
#define GLD16(gp, lp) __builtin_amdgcn_global_load_lds( \
    (const __attribute__((address_space(1))) void*)(gp), \
    (__attribute__((address_space(3))) void*)(lp), 16, 0, 0)
#endif

#ifdef HAS_PKRTZ
#define PKF16(a, b) __builtin_amdgcn_cvt_pkrtz((a), (b))
#else
#define PKF16(a, b) ((fp16x2){ (__fp16)(a), (__fp16)(b) })
#endif

// ---------------------------------------------------------------------------
// Fused conversion kernel (one launch): every block locally detects the input
// dtype from x's first 4096 halfwords, then converts its assigned slice.
// ---------------------------------------------------------------------------
__global__ __launch_bounds__(256) void fused_conv(
        const void* __restrict__ xin,
        const void* __restrict__ w0, const void* __restrict__ w1,
        const void* __restrict__ w2, const void* __restrict__ w3,
        const void* __restrict__ b0, const void* __restrict__ b1,
        const void* __restrict__ b2, const void* __restrict__ b3,
        short* __restrict__ xc, short* __restrict__ wt,
        short* __restrict__ bc, int* __restrict__ flag)
{
    __shared__ int red[256];
    __shared__ float T[64][65];
    const int tid = threadIdx.x;
    const int F = blockIdx.x;

    {
        const short* xs = (const short*)xin;
        int maxe = 0;
#pragma unroll
        for (int u = 0; u < 16; ++u) {
            int e = ((unsigned short)xs[tid * 16 + u] >> 7) & 0xFF;
            maxe = max(maxe, e);
        }
        red[tid] = maxe;
        __syncthreads();
        for (int s = 128; s > 0; s >>= 1) {
            if (tid < s) red[tid] = max(red[tid], red[tid + s]);
            __syncthreads();
        }
    }
    const bool isf = (red[0] > 140);

    if (F < 3072) {
        const int i = F * 256 + tid;
        if (isf) {
            float4 f = ((const float4*)xin)[i];
            short4 o = { f2bf(f.x), f2bf(f.y), f2bf(f.z), f2bf(f.w) };
            ((short4*)xc)[i] = o;
        } else {
            ((short4*)xc)[i] = ((const short4*)xin)[i];
        }
    } else if (F < 3648) {
        const int G = F - 3072;
        const int z = G / 144, rr = G % 144;
        const int k0 = (rr % 12) * 64, n0 = (rr / 12) * 64;
        const void* src = (z == 0) ? w0 : (z == 1) ? w1 : (z == 2) ? w2 : w3;
        const float sc = (z == 0) ? SC_LOG2 : 1.0f;
        const int la = tid & 15, lb = tid >> 4;
#pragma unroll
        for (int u = 0; u < 4; ++u) {
            const int kr = (lb & 3) + 4 * u + 16 * (lb >> 2);
            if (isf) {
                float4 f = *(const float4*)((const float*)src + (size_t)(k0 + kr) * D_MODEL + n0 + la * 4);
                T[kr][la*4+0] = f.x; T[kr][la*4+1] = f.y; T[kr][la*4+2] = f.z; T[kr][la*4+3] = f.w;
            } else {
                short4 s = *(const short4*)((const short*)src + (size_t)(k0 + kr) * D_MODEL + n0 + la * 4);
                T[kr][la*4+0] = bf2f(s.x); T[kr][la*4+1] = bf2f(s.y);
                T[kr][la*4+2] = bf2f(s.z); T[kr][la*4+3] = bf2f(s.w);
            }
        }
        __syncthreads();
#pragma unroll
        for (int u = 0; u < 4; ++u) {
            const int nr = (lb & 3) + 4 * u + 16 * (lb >> 2);
            short4 o = { f2bf(T[la*4+0][nr] * sc), f2bf(T[la*4+1][nr] * sc),
                         f2bf(T[la*4+2][nr] * sc), f2bf(T[la*4+3][nr] * sc) };
            *(short4*)(wt + (size_t)z * NW + (size_t)(n0 + nr) * D_MODEL + k0 + la * 4) = o;
        }
    } else {
        if (tid == 0) *flag = isf ? 1 : 0;
        const void* srcs[4] = { b0, b1, b2, b3 };
        for (int z = 0; z < 4; ++z) {
            const float sc = (z == 0) ? SC_LOG2 : 1.0f;
            for (int i = tid; i < D_MODEL; i += 256) {
                float v = isf ? ((const float*)srcs[z])[i] : bf2f(((const short*)srcs[z])[i]);
                bc[z * D_MODEL + i] = f2bf(v * sc);
            }
        }
    }
}

// ---------------------------------------------------------------------------
// Fused QKV GEMM R19: 128M x 128N tiles, 512 thr / 8 waves (R18 structure).
// NEW: K and V outputs are written in the attention kernel's LDS-image TILED
// layouts, so attn staging becomes contiguous coalesced GLD16 (each tile is
// written once here, staged 16x by attn -> producer-side swizzle wins 16:1):
//   kb[bh][tile32][chunk8][key64][8dims]   (8KB per 64-key tile, bf16)
//   Vt[bh][tile32][kchunk8][dim64][8keys]  (8KB per 64-key tile, f16)
// Q output stays row-major [token][768].
// ---------------------------------------------------------------------------
__global__ __launch_bounds__(512) void qkv_gemm(const short* __restrict__ X,
                                                const short* __restrict__ Wt,
                                                const short* __restrict__ bias,
                                                short* __restrict__ qb,
                                                short* __restrict__ kb,
                                                _Float16* __restrict__ Vt)
{
    __shared__ __align__(16) char shbuf[32768];
    short* Als = (short*)shbuf;               // [2][4096] = 128 rows x 32
    short* Bls = (short*)(shbuf + 16384);     // [2][4096]
    _Float16* T = (_Float16*)shbuf;           // epilogue: 128*72 f16 = 18432 B

    const int tid = threadIdx.x;
    const int wave = tid >> 6, lane = tid & 63;
    const int quad = lane >> 4, l16 = lane & 15;
    const int wm = wave & 3, wn = wave >> 2;
    const int m0 = blockIdx.x * 128;
    const int ng = blockIdx.y * 128;

    f32x4 acc[2][4];
#pragma unroll
    for (int nt = 0; nt < 4; ++nt) {
        const float bv = bf2f(bias[ng + wn*64 + nt*16 + l16]);
#pragma unroll
        for (int mt = 0; mt < 2; ++mt) acc[mt][nt] = (f32x4){bv, bv, bv, bv};
    }

    const int row = tid >> 2, ch = (tid & 3) * 8;   // row 0..127, ch 0/8/16/24
#ifdef HAS_GLD
#define QSTAGE(buf, k0) do { \
        GLD16(X  + (size_t)(m0 + row) * D_MODEL + (k0) + ch, &Als[(buf)*4096 + tid*8]); \
        GLD16(Wt + (size_t)(ng + row) * D_MODEL + (k0) + ch, &Bls[(buf)*4096 + tid*8]); \
    } while (0)
#else
#define QSTAGE(buf, k0) do { \
        short8 r0 = *(const short8*)(X  + (size_t)(m0 + row) * D_MODEL + (k0) + ch); \
        short8 r1 = *(const short8*)(Wt + (size_t)(ng + row) * D_MODEL + (k0) + ch); \
        *(short8*)&Als[(buf)*4096 + tid*8] = r0; \
        *(short8*)&Bls[(buf)*4096 + tid*8] = r1; \
    } while (0)
#endif

    QSTAGE(0, 0);
    __syncthreads();

    for (int ks = 0; ks < 24; ++ks) {
        const int cur = ks & 1;
        if (ks + 1 < 24) QSTAGE(cur ^ 1, (ks + 1) * 32);

        short8 a[2], b[4];
#pragma unroll
        for (int mt = 0; mt < 2; ++mt)
            a[mt] = *(const short8*)&Als[cur*4096 + (wm*32 + mt*16 + l16) * 32 + quad*8];
#pragma unroll
        for (int nt = 0; nt < 4; ++nt)
            b[nt] = *(const short8*)&Bls[cur*4096 + (wn*64 + nt*16 + l16) * 32 + quad*8];
#pragma unroll
        for (int mt = 0; mt < 2; ++mt)
#pragma unroll
        for (int nt = 0; nt < 4; ++nt)
            acc[mt][nt] = __builtin_amdgcn_mfma_f32_16x16x32_bf16(a[mt], b[nt], acc[mt][nt], 0, 0, 0);

        __syncthreads();
    }
#undef QSTAGE

    const int seg = blockIdx.y / 6;   // 0=q, 1=k, 2=v
    if (seg == 0) {
#pragma unroll
        for (int mt = 0; mt < 2; ++mt)
#pragma unroll
        for (int nt = 0; nt < 4; ++nt) {
            const int n = ng + wn*64 + nt*16 + l16;
#pragma unroll
            for (int r = 0; r < 4; ++r) {
                const int m = m0 + wm*32 + mt*16 + quad*4 + r;
                qb[(size_t)m * D_MODEL + n] = f2bf(acc[mt][nt][r]);
            }
        }
    } else if (seg == 1) {
        // K -> tiled [bh][tile][chunk8][key64][8dims]
        const int nl = ng - 768;
#pragma unroll
        for (int mt = 0; mt < 2; ++mt)
#pragma unroll
        for (int nt = 0; nt < 4; ++nt) {
            const int n = nl + wn*64 + nt*16 + l16;      // 0..767
            const int h = n >> 6, dh = n & 63;
            const int chunk = dh >> 3, dof = dh & 7;
#pragma unroll
            for (int r = 0; r < 4; ++r) {
                const int m = m0 + wm*32 + mt*16 + quad*4 + r;
                const int b2 = m >> 11, tok = m & (SEQ - 1);
                kb[((size_t)(b2*NHEADS + h)*32 + (tok >> 6))*4096
                   + chunk*512 + (tok & 63)*8 + dof] = f2bf(acc[mt][nt][r]);
            }
        }
    } else {
        // V -> tiled [bh][tile][kchunk8][dim64][8keys], two 64-token passes
        const int batch = m0 >> 11, tokb0 = m0 & (SEQ - 1);
#pragma unroll
        for (int p = 0; p < 2; ++p) {
            if ((wm >> 1) == p) {
#pragma unroll
                for (int nt = 0; nt < 4; ++nt) {
                    const int dim_l = wn*64 + nt*16 + l16;
#pragma unroll
                    for (int mt = 0; mt < 2; ++mt) {
                        const int tok_l = (wm & 1)*32 + mt*16 + quad*4;
                        union { _Float16 h4[4]; int2 v; } u;
#pragma unroll
                        for (int r = 0; r < 4; ++r) u.h4[r] = (_Float16)acc[mt][nt][r];
                        *(int2*)&T[dim_l * 72 + tok_l] = u.v;
                    }
                }
            }
            __syncthreads();
#pragma unroll
            for (int u = 0; u < 2; ++u) {
                const int slot = tid + u * 512;        // 0..1023 = 8 chunks x 128 dims
                const int drow = slot & 127, chk = slot >> 7;
                int4 val = *(const int4*)&T[drow * 72 + chk * 8];
                const int dim_g = ng - 1536 + drow;
                const int h = dim_g >> 6, dl = dim_g & 63;
                *(int4*)(Vt + ((size_t)((batch*NHEADS + h)*32) + (tokb0 >> 6) + p)*4096
                            + chk*512 + dl*8) = val;
            }
            if (p == 0) __syncthreads();   // T reused by pass 1
        }
    }
}

// ---------------------------------------------------------------------------
// Output projection R18 (unchanged): fused combine with T14 async split.
// ---------------------------------------------------------------------------
__global__ __launch_bounds__(256) void out_gemm(const _Float16* __restrict__ Op,
                                                const float* __restrict__ mlp,
                                                const short* __restrict__ Wt,
                                                const short* __restrict__ bias,
                                                void* __restrict__ outv,
                                                const int* __restrict__ flag)
{
    __shared__ short Als[2][2048];
    __shared__ short Bls[2][2048];

    const int tid = threadIdx.x;
    const int wave = tid >> 6, lane = tid & 63;
    const int quad = lane >> 4, l16 = lane & 15;
    const int m0 = blockIdx.x * 64;
    const int n0 = blockIdx.y * 64;

    f32x4 acc[4];
#pragma unroll
    for (int nt = 0; nt < 4; ++nt) {
        const float bv = bf2f(bias[n0 + nt*16 + l16]);
        acc[nt] = (f32x4){bv, bv, bv, bv};
    }

    const int row = tid >> 2, ch = (tid & 3) * 8;
    const int m = m0 + row;
    const int bhb = (m >> 11) * NHEADS;      // batch * NHEADS
    const int qq = m & (SEQ - 1);
    const _Float16* Op2 = Op + (size_t)(NBH * SEQ) * HD;

#define XLOAD(ks) do { \
        const int cc = (ks) * 32 + ch; \
        const int h = cc >> 6, d = cc & 63; \
        const size_t r1 = (size_t)(bhb + h) * SEQ + qq; \
        const float2 ml1 = *(const float2*)&mlp[r1 * 2]; \
        const float2 ml2 = *(const float2*)&mlp[((size_t)(NBH * SEQ) + r1) * 2]; \
        p1 = *(const half8*)&Op[r1 * HD + d]; \
        p2 = *(const half8*)&Op2[r1 * HD + d]; \
        const float M_ = fmaxf(ml1.x, ml2.x); \
        const float w1 = EXP2(ml1.x - M_) * ml1.y; \
        const float w2 = EXP2(ml2.x - M_) * ml2.y; \
        const float s_ = 1.0f / (w1 + w2); \
        f1 = w1 * s_; f2 = w2 * s_; \
    } while (0)

#define XSTORE(buf) do { \
        short8 xb; \
        _Pragma("unroll") \
        for (int j = 0; j < 8; ++j) \
            xb[j] = f2bf(f1 * (float)p1[j] + f2 * (float)p2[j]); \
        *(short8*)&Als[buf][tid*8] = xb; \
    } while (0)

#ifdef HAS_GLD
#define BSTAGE(buf, k0) \
        GLD16(Wt + (size_t)(n0 + row) * D_MODEL + (k0) + ch, &Bls[buf][tid*8])
#else
#define BSTAGE(buf, k0) do { \
        short8 r1_ = *(const short8*)(Wt + (size_t)(n0 + row) * D_MODEL + (k0) + ch); \
        *(short8*)&Bls[buf][tid*8] = r1_; } while (0)
#endif

    half8 p1, p2; float f1, f2;
    XLOAD(0); XSTORE(0);
    BSTAGE(0, 0);
    __syncthreads();

    for (int ks = 0; ks < 24; ++ks) {
        const int cur = ks & 1;
        if (ks + 1 < 24) {
            XLOAD(ks + 1);             // issue loads early (T14)
            BSTAGE(cur ^ 1, (ks + 1) * 32);
        }

        short8 a = *(const short8*)&Als[cur][(wave*16 + l16) * 32 + quad*8];
#pragma unroll
        for (int nt = 0; nt < 4; ++nt) {
            short8 b = *(const short8*)&Bls[cur][(nt*16 + l16) * 32 + quad*8];
            acc[nt] = __builtin_amdgcn_mfma_f32_16x16x32_bf16(a, b, acc[nt], 0, 0, 0);
        }

        if (ks + 1 < 24) XSTORE(cur ^ 1);   // convert + LDS write late
        __syncthreads();
    }
#undef XLOAD
#undef XSTORE
#undef BSTAGE

    const bool outf32 = (*flag != 0);
#pragma unroll
    for (int nt = 0; nt < 4; ++nt) {
        const int n = n0 + nt*16 + l16;
#pragma unroll
        for (int r = 0; r < 4; ++r) {
            const int mm = m0 + wave*16 + quad*4 + r;
            const size_t idx = (size_t)mm * D_MODEL + n;
            if (outf32) ((float*)outv)[idx] = acc[nt][r];
            else        ((short*)outv)[idx] = f2bf(acc[nt][r]);
        }
    }
}

// ---------------------------------------------------------------------------
// Flash attention R19: R16 body (verified 3x, ~46.5us) with COALESCED tiled
// staging. kb/Vt are now produced in the exact LDS-image tile layout, so
// STAGE_K/STAGE_V read a contiguous 8KB block (thread tid -> tid*16B):
// before, lanes read 16B at 1536B/4KB strides (64 lines/instr, 4x L2 line
// over-fetch) and every barrier's vmcnt(0) drain waited on them.
// ---------------------------------------------------------------------------
__global__ __launch_bounds__(256, 3) void attn_mfma(const short* __restrict__ q,
                                                    const short* __restrict__ k,
                                                    const _Float16* __restrict__ Vt,
                                                    _Float16* __restrict__ Op,
                                                    float* __restrict__ mlp)
{
    __shared__ __align__(16) short    Kls[2][4096];   // [8 dimchunk][64 key][8] bf16, 8KB/buf
    __shared__ __align__(16) _Float16 Vls[2][4096];   // [8 keychunk][64 dim][8] f16, 8KB/buf
    __shared__ __align__(16) _Float16 Pls[4][2048];   // per-wave [col][8 keychunk][16 q][8]

    const int tid  = threadIdx.x;
    const int wave = tid >> 6, lane = tid & 63;
    const int quad = lane >> 4, l16 = lane & 15;

    const int F = blockIdx.x;               // 768 = 8 xcd * 96
    const int xcd = F & 7, slot = F >> 3;   // slot 0..95
    const int bh = xcd * 3 + (slot >> 5);   // 3 heads per XCD (KV L2-resident)
    const int rem = slot & 31;
    const int q0 = (rem >> 1) * 128;        // 16 q-blocks of 128
    const int sp = rem & 1;                 // KV split index
    const int b = bh / NHEADS, h = bh % NHEADS;
    const size_t bS = (size_t)b * SEQ;

    // two 16-q columns per wave
    short8 qf[2][2];
#pragma unroll
    for (int col = 0; col < 2; ++col)
#pragma unroll
    for (int k0h = 0; k0h < 2; ++k0h)
        qf[col][k0h] = *(const short8*)(q + (bS + q0 + wave*32 + col*16 + l16) * D_MODEL
                                          + h*HD + k0h*32 + quad*8);

    half8 ones;
#pragma unroll
    for (int j = 0; j < 8; ++j) ones[j] = (_Float16)1.0f;

    // tiled staging bases: tile = sp*16 + j0/64, 4096 elems (8KB) per tile
    const short*    kbase = k  + ((size_t)bh*32 + sp*16) * 4096;
    const _Float16* vbase = Vt + ((size_t)bh*32 + sp*16) * 4096;

#ifdef HAS_GLD
#define STAGE_K(buf, j0) do { \
        GLD16(kbase + (size_t)(j0)*64 + tid*8,       &Kls[buf][tid*8]); \
        GLD16(kbase + (size_t)(j0)*64 + (tid+256)*8, &Kls[buf][(tid+256)*8]); \
    } while (0)
#define STAGE_V(buf, j0) do { \
        GLD16(vbase + (size_t)(j0)*64 + tid*8,       &Vls[buf][tid*8]); \
        GLD16(vbase + (size_t)(j0)*64 + (tid+256)*8, &Vls[buf][(tid+256)*8]); \
    } while (0)
#else
#define STAGE_K(buf, j0) do { \
        short8 a_ = *(const short8*)(kbase + (size_t)(j0)*64 + tid*8); \
        short8 b_ = *(const short8*)(kbase + (size_t)(j0)*64 + (tid+256)*8); \
        *(short8*)&Kls[buf][tid*8] = a_;  *(short8*)&Kls[buf][(tid+256)*8] = b_; \
    } while (0)
#define STAGE_V(buf, j0) do { \
        half8 c_ = *(const half8*)(vbase + (size_t)(j0)*64 + tid*8); \
        half8 d_ = *(const half8*)(vbase + (size_t)(j0)*64 + (tid+256)*8); \
        *(half8*)&Vls[buf][tid*8] = c_;  *(half8*)&Vls[buf][(tid+256)*8] = d_; \
    } while (0)
#endif

    float m_ = -1e30f;
    f32x4 laccA = (f32x4){0.f,0.f,0.f,0.f}, laccB = (f32x4){0.f,0.f,0.f,0.f};
    f32x4 o[4][2];
#pragma unroll
    for (int t = 0; t < 4; ++t) { o[t][0] = (f32x4){0.f,0.f,0.f,0.f}; o[t][1] = (f32x4){0.f,0.f,0.f,0.f}; }

#define NT (SEQ / 2 / 64)   // 16 iterations over this split's keys

// QK^T of 64-key tile in K-buffer KB into transient logits S. One kf read
// feeds BOTH q-columns.
#define QK(S, KB) do { \
    _Pragma("unroll") \
    for (int t = 0; t < 4; ++t) { S[t][0] = (f32x4){0.f,0.f,0.f,0.f}; S[t][1] = (f32x4){0.f,0.f,0.f,0.f}; } \
    _Pragma("unroll") \
    for (int k0h = 0; k0h < 2; ++k0h) \
    _Pragma("unroll") \
    for (int t = 0; t < 4; ++t) { \
        short8 kf = *(const short8*)&Kls[KB][(k0h*4 + quad)*512 + (t*16 + l16)*8]; \
        S[t][0] = __builtin_amdgcn_mfma_f32_16x16x32_bf16(kf, qf[0][k0h], S[t][0], 0, 0, 0); \
        S[t][1] = __builtin_amdgcn_mfma_f32_16x16x32_bf16(kf, qf[1][k0h], S[t][1], 0, 0, 0); \
    } \
} while (0)

// PV of tile in V-buffer VB, P from per-wave Pls (written previous body)
#define PV(VB) do { \
    _Pragma("unroll") \
    for (int k0h = 0; k0h < 2; ++k0h) { \
        half8 pf0 = *(half8*)&Pls[wave][(k0h*4 + quad)*128 + l16*8]; \
        half8 pf1 = *(half8*)&Pls[wave][1024 + (k0h*4 + quad)*128 + l16*8]; \
        laccA = __builtin_amdgcn_mfma_f32_16x16x32_f16(ones, pf0, laccA, 0, 0, 0); \
        laccB = __builtin_amdgcn_mfma_f32_16x16x32_f16(ones, pf1, laccB, 0, 0, 0); \
        _Pragma("unroll") \
        for (int t = 0; t < 4; ++t) { \
            half8 vf = *(const half8*)&Vls[VB][(k0h*4 + quad)*512 + (t*16 + l16)*8]; \
            o[t][0] = __builtin_amdgcn_mfma_f32_16x16x32_f16(vf, pf0, o[t][0], 0, 0, 0); \
            o[t][1] = __builtin_amdgcn_mfma_f32_16x16x32_f16(vf, pf1, o[t][1], 0, 0, 0); \
        } \
    } \
} while (0)

// softmax on transient logits S: deferred max (THR=8, log2 domain), rescale
// o/lacc, pack P to f16, store to per-wave Pls (chunk-major).
#define SOFTMAX(S) do { \
    float mx = S[0][0][0]; \
    _Pragma("unroll") \
    for (int t = 0; t < 4; ++t) \
    _Pragma("unroll") \
    for (int c = 0; c < 2; ++c) \
    _Pragma("unroll") \
    for (int r = 0; r < 4; ++r) mx = fmaxf(mx, S[t][c][r]); \
    if (__any(mx > m_ + 8.f)) { \
        _Pragma("unroll") \
        for (int d = 1; d < 64; d <<= 1) mx = fmaxf(mx, __shfl_xor(mx, d)); \
        const float mn = fmaxf(m_, mx); \
        const float al = EXP2(m_ - mn); \
        _Pragma("unroll") \
        for (int t = 0; t < 4; ++t) \
        _Pragma("unroll") \
        for (int c = 0; c < 2; ++c) { \
            o[t][c][0] *= al; o[t][c][1] *= al; o[t][c][2] *= al; o[t][c][3] *= al; \
        } \
        laccA[0] *= al; laccB[0] *= al; \
        m_ = mn; \
    } \
    _Pragma("unroll") \
    for (int t = 0; t < 4; ++t) \
    _Pragma("unroll") \
    for (int c = 0; c < 2; ++c) { \
        union { fp16x2 h2[2]; int2 v; } u4; \
        u4.h2[0] = PKF16(EXP2(S[t][c][0] - m_), EXP2(S[t][c][1] - m_)); \
        u4.h2[1] = PKF16(EXP2(S[t][c][2] - m_), EXP2(S[t][c][3] - m_)); \
        const int kc = 2*t + (quad >> 1); \
        *(int2*)&Pls[wave][c*1024 + kc*128 + l16*8 + (quad & 1)*4] = u4.v; \
    } \
} while (0)

// One iteration: stage K(j+2) & V(j+1); QK(j+1); PV(j); softmax(j+1); barrier
#define BODY(JT) do { \
    if ((JT) + 2 < NT) STAGE_K(((JT) + 2) & 1, ((JT) + 2) * 64); \
    if ((JT) + 1 < NT) STAGE_V(((JT) + 1) & 1, ((JT) + 1) * 64); \
    f32x4 s_[4][2]; \
    __builtin_amdgcn_s_setprio(1); \
    if ((JT) + 1 < NT) QK(s_, ((JT) + 1) & 1); \
    PV((JT) & 1); \
    __builtin_amdgcn_s_setprio(0); \
    if ((JT) + 1 < NT) SOFTMAX(s_); \
    __syncthreads(); \
} while (0)

    // ---- prologue: K0,V0 staged+drained; K1 staged; QK(0)+softmax(0) ----
    STAGE_K(0, 0); STAGE_V(0, 0);
    __syncthreads();
    STAGE_K(1, 64);
    {
        f32x4 s_[4][2];
        QK(s_, 0);
        SOFTMAX(s_);     // P(0) -> Pls
    }
    __syncthreads();     // drains STAGE_K(1)

    for (int jt = 0; jt < NT; ++jt) BODY(jt);

    // ---- normalized f16 partials + (m, l) per column ----
#pragma unroll
    for (int col = 0; col < 2; ++col) {
        const f32x4 la = col ? laccB : laccA;
        const float inv = 1.0f / la[0];
        const int myq = q0 + wave*32 + col*16 + l16;
        const size_t prow = ((size_t)sp * (NBH * SEQ) + (size_t)bh * SEQ + myq);
        _Float16* orow = Op + prow * HD;
#pragma unroll
        for (int t = 0; t < 4; ++t) {
            union { _Float16 h4[4]; int2 v; } u4;
#pragma unroll
            for (int r = 0; r < 4; ++r) u4.h4[r] = (_Float16)(o[t][col][r] * inv);
            *(int2*)(orow + t*16 + quad*4) = u4.v;
        }
        if (quad == 0) {
            float2 mlv; mlv.x = m_; mlv.y = la[0];
            *(float2*)&mlp[prow * 2] = mlv;
        }
    }
#undef BODY
#undef SOFTMAX
#undef PV
#undef QK
#undef NT
#undef STAGE_K
#undef STAGE_V
}

// ---------------------------------------------------------------------------
extern "C" void kernel_launch(void* const* d_in, const int* in_sizes, int n_in,
                              void* d_out, int out_size, void* d_ws, size_t ws_size,
                              hipStream_t stream)
{
    int* flag = (int*)d_ws;
    short* xc = (short*)((char*)d_ws + 64);
    short* Wt = xc + NX;                 // 4 transposed weights q|k|v|o
    short* bc = Wt + 4 * NW;             // biases q|k|v|o
    short* qb = bc + 4 * D_MODEL;
    short* kb = qb + NX;                 // tiled K [bh][32][4096]
    _Float16* Vt = (_Float16*)(kb + NX); // tiled V [bh][32][4096]
    _Float16* Op = (_Float16*)(Vt + NX); // 2 x [24][2048][64] f16 partials
    float* mlp = (float*)(Op + (size_t)2 * NBH * SEQ * HD);  // 2 x [24][2048] (m,l)

    fused_conv<<<3649, 256, 0, stream>>>(d_in[0],
                                         d_in[1], d_in[3], d_in[5], d_in[7],
                                         d_in[2], d_in[4], d_in[6], d_in[8],
                                         xc, Wt, bc, flag);

    qkv_gemm<<<dim3(NTOK/128, 2304/128), 512, 0, stream>>>(xc, Wt, bc, qb, kb, Vt);

    attn_mfma<<<768, 256, 0, stream>>>(qb, kb, Vt, Op, mlp);

    out_gemm<<<dim3(NTOK/64, D_MODEL/64), 256, 0, stream>>>(Op, mlp, Wt + 3*NW, bc + 3*D_MODEL, d_out, flag);
}